// Round 5
// baseline (393.539 us; speedup 1.0000x reference)
//
#include <hip/hip_runtime.h>

// ---------------------------------------------------------------------------
// MultiHeadedAttention fused pipeline for MI355X (gfx950), bf16 MFMA.
// B=1, S=4096, D=768, H=12, DH=64.
// Round 5: round-2 fast path + THE fix: d_out is FLOAT32 (proven by round-3
// sentinel decode: bf16 pair read as f32 word 0x4380xxxx = 258). k_proj now
// stores f32. All compute verified correct by round-4 oracle equivalence.
// Workspace layout (bytes):
//   xb   [4096][768] bf16          @ 0         (6291456)
//   wT   [3][12][64][768] bf16     @ 6291456   (3538944)   (B^T of per-head W)
//   woT  [768][768] bf16           @ 9830400   (1179648)   (woT[j][i] = wo[i][j])
//   q    [12][4096][64] bf16       @ 11010048  (6291456)   (pre-scaled by 1/8)
//   k    [12][4096][64] bf16       @ 17301504  (6291456)
//   vT   [12][64][4096] bf16       @ 23592960  (6291456)
//   ctx  [4096][768] bf16          @ 29884416  (6291456)
// total 36175872 bytes (~34.5 MB); ws_size >= 48 MB proven.
// ---------------------------------------------------------------------------

using frag8 = __attribute__((ext_vector_type(8))) short;   // 8 x bf16 (4 VGPRs)
using facc4 = __attribute__((ext_vector_type(4))) float;   // MFMA accumulator

#define LOG2E 1.4426950408889634f

#if defined(__has_builtin)
#  if __has_builtin(__builtin_amdgcn_exp2f)
#    define EXP2(x) __builtin_amdgcn_exp2f(x)
#  else
#    define EXP2(x) exp2f(x)
#  endif
#else
#  define EXP2(x) exp2f(x)
#endif

__device__ __forceinline__ unsigned short f2bf(float f) {
  unsigned int u = __builtin_bit_cast(unsigned int, f);
  u = (u + 0x7FFFu + ((u >> 16) & 1u)) >> 16;   // RNE
  return (unsigned short)u;
}

__device__ __forceinline__ facc4 mfma_bf16(frag8 a, frag8 b, facc4 c) {
  return __builtin_amdgcn_mfma_f32_16x16x32_bf16(a, b, c, 0, 0, 0);
}

// ---------------------------------------------------------------------------
// x f32 -> bf16, 8 elems/thread. N = 3145728 = 1536*256*8 exactly.
__global__ __launch_bounds__(256) void k_cvt_x(const float* __restrict__ in,
                                               unsigned short* __restrict__ out) {
  int i = (blockIdx.x * 256 + threadIdx.x) * 8;
  float4 a = *(const float4*)(in + i);
  float4 b = *(const float4*)(in + i + 4);
  frag8 r;
  r[0] = (short)f2bf(a.x); r[1] = (short)f2bf(a.y);
  r[2] = (short)f2bf(a.z); r[3] = (short)f2bf(a.w);
  r[4] = (short)f2bf(b.x); r[5] = (short)f2bf(b.y);
  r[6] = (short)f2bf(b.z); r[7] = (short)f2bf(b.w);
  *(frag8*)(out + i) = r;
}

// ---------------------------------------------------------------------------
// Weight transpose+convert: 64x64 f32 tiles -> bf16 transposed.
__global__ __launch_bounds__(256) void k_prep_w(
    const float* __restrict__ wq, const float* __restrict__ wk,
    const float* __restrict__ wv, const float* __restrict__ wo,
    unsigned short* __restrict__ wqT, unsigned short* __restrict__ wkT,
    unsigned short* __restrict__ wvT, unsigned short* __restrict__ woT) {
  __shared__ unsigned short tile[64][65];
  const int bx = blockIdx.x;
  const float* src; unsigned short* dst;
  int ld_src, ld_dst, r0, c0;
  if (bx < 432) {
    int p = bx / 144, rem = bx % 144;
    int h = rem / 12, dt = rem % 12;
    src = (p == 0 ? wq : (p == 1 ? wk : wv)) + (size_t)h * 768 * 64;
    dst = (p == 0 ? wqT : (p == 1 ? wkT : wvT)) + (size_t)h * 64 * 768;
    ld_src = 64; ld_dst = 768; r0 = dt * 64; c0 = 0;
  } else {
    int t = bx - 432;
    src = wo; dst = woT;
    ld_src = 768; ld_dst = 768;
    r0 = (t / 12) * 64; c0 = (t % 12) * 64;
  }
  const int tid = threadIdx.x;
  const int lr = tid >> 2, lc0 = (tid & 3) * 16;
#pragma unroll
  for (int i = 0; i < 16; ++i)
    tile[lr][lc0 + i] = f2bf(src[(size_t)(r0 + lr) * ld_src + c0 + lc0 + i]);
  __syncthreads();
  const int oc = tid >> 2;
#pragma unroll
  for (int i = 0; i < 16; ++i)
    dst[(size_t)(c0 + oc) * ld_dst + r0 + lc0 + i] = tile[lc0 + i][oc];
}

// ---------------------------------------------------------------------------
// QKV projection GEMM: out[s,e] = sum_d xb[s,d]*wT[ph][e,d]  (+bias, q scaled)
// grid (32, 36): 128-row s-tile x (proj*12+head). 4 waves as 2x2 -> 64x32 each.
__global__ __launch_bounds__(256) void k_qkv(
    const unsigned short* __restrict__ xb, const unsigned short* __restrict__ wT,
    const float* __restrict__ bq, const float* __restrict__ bk,
    const float* __restrict__ bv,
    unsigned short* __restrict__ qo, unsigned short* __restrict__ ko,
    unsigned short* __restrict__ vTo) {
  __shared__ __align__(16) unsigned short As[128 * 72];
  __shared__ __align__(16) unsigned short Bs[64 * 72];
  const int sb = blockIdx.x, ph = blockIdx.y;
  const int p = ph / 12, h = ph % 12;
  const int s0 = sb * 128;
  const int tid = threadIdx.x;
  const int w = tid >> 6, l = tid & 63;
  const int lg = l >> 4, li = l & 15;
  const int wm = w >> 1, wn = w & 1;
  const unsigned short* wTb = wT + (size_t)ph * 64 * 768;

  facc4 acc[4][2];
#pragma unroll
  for (int i = 0; i < 4; ++i)
#pragma unroll
    for (int j = 0; j < 2; ++j) acc[i][j] = (facc4){0.f, 0.f, 0.f, 0.f};

  const int rA = tid >> 3;
  const int c8 = (tid & 7) * 8;

  for (int k0 = 0; k0 < 768; k0 += 64) {
    frag8 av[4], bw[2];
#pragma unroll
    for (int i = 0; i < 4; ++i)
      av[i] = *(const frag8*)(xb + (size_t)(s0 + i * 32 + rA) * 768 + k0 + c8);
#pragma unroll
    for (int i = 0; i < 2; ++i)
      bw[i] = *(const frag8*)(wTb + (size_t)(i * 32 + rA) * 768 + k0 + c8);
#pragma unroll
    for (int i = 0; i < 4; ++i)
      *(frag8*)(&As[(i * 32 + rA) * 72 + c8]) = av[i];
#pragma unroll
    for (int i = 0; i < 2; ++i)
      *(frag8*)(&Bs[(i * 32 + rA) * 72 + c8]) = bw[i];
    __syncthreads();
#pragma unroll
    for (int kk = 0; kk < 2; ++kk) {
      const int ce = kk * 32 + lg * 8;
      frag8 a[4], b[2];
#pragma unroll
      for (int mf = 0; mf < 4; ++mf)
        a[mf] = *(const frag8*)(&As[(wm * 64 + mf * 16 + li) * 72 + ce]);
#pragma unroll
      for (int nf = 0; nf < 2; ++nf)
        b[nf] = *(const frag8*)(&Bs[(wn * 32 + nf * 16 + li) * 72 + ce]);
#pragma unroll
      for (int mf = 0; mf < 4; ++mf)
#pragma unroll
        for (int nf = 0; nf < 2; ++nf)
          acc[mf][nf] = mfma_bf16(a[mf], b[nf], acc[mf][nf]);
    }
    __syncthreads();
  }

  const float* bias = (p == 0 ? bq : (p == 1 ? bk : bv)) + h * 64;
  const float scale = (p == 0) ? 0.125f : 1.0f;   // 1/sqrt(DH) folded into q
  float bvv[2];
#pragma unroll
  for (int nf = 0; nf < 2; ++nf) bvv[nf] = bias[wn * 32 + nf * 16 + li];
#pragma unroll
  for (int mf = 0; mf < 4; ++mf)
#pragma unroll
    for (int nf = 0; nf < 2; ++nf) {
      int e = wn * 32 + nf * 16 + li;
#pragma unroll
      for (int j = 0; j < 4; ++j) {
        int s = s0 + wm * 64 + mf * 16 + lg * 4 + j;   // C: row=(l>>4)*4+reg
        unsigned short bf = f2bf((acc[mf][nf][j] + bvv[nf]) * scale);
        if (p == 0)      qo[((size_t)h * 4096 + s) * 64 + e] = bf;
        else if (p == 1) ko[((size_t)h * 4096 + s) * 64 + e] = bf;
        else             vTo[((size_t)h * 64 + e) * 4096 + s] = bf;  // V^T
      }
    }
}

// ---------------------------------------------------------------------------
// Flash attention: grid 768 = 12 heads x 64 q-blocks(64 rows). 4 waves x 16 rows.
__global__ __launch_bounds__(256) void k_attn(
    const unsigned short* __restrict__ q, const unsigned short* __restrict__ k,
    const unsigned short* __restrict__ vT, unsigned short* __restrict__ ctx) {
  __shared__ __align__(16) unsigned short Pb[4][16 * 72];
  const int bid = blockIdx.x;
  const int h = bid >> 6, qb = bid & 63;
  const int s0 = qb * 64;
  const int tid = threadIdx.x;
  const int w = tid >> 6, l = tid & 63;
  const int lg = l >> 4, li = l & 15;
  unsigned short* P = &Pb[w][0];
  const unsigned short* Kh = k + (size_t)h * 4096 * 64;
  const unsigned short* Vh = vT + (size_t)h * 64 * 4096;

  const unsigned short* qrow = q + ((size_t)h * 4096 + s0 + w * 16 + li) * 64;
  frag8 qf0 = *(const frag8*)(qrow + lg * 8);
  frag8 qf1 = *(const frag8*)(qrow + 32 + lg * 8);

  float m[4], lsum[4];
  facc4 acc[4];
#pragma unroll
  for (int j = 0; j < 4; ++j) { m[j] = -1e30f; lsum[j] = 0.f; }
#pragma unroll
  for (int nf = 0; nf < 4; ++nf) acc[nf] = (facc4){0.f, 0.f, 0.f, 0.f};

  for (int kt = 0; kt < 64; ++kt) {
    const int kbase = kt * 64;
    facc4 sf[4];
#pragma unroll
    for (int cn = 0; cn < 4; ++cn) sf[cn] = (facc4){0.f, 0.f, 0.f, 0.f};
#pragma unroll
    for (int cn = 0; cn < 4; ++cn) {
      const unsigned short* kp = Kh + (size_t)(kbase + cn * 16 + li) * 64 + lg * 8;
      frag8 b0 = *(const frag8*)kp;
      frag8 b1 = *(const frag8*)(kp + 32);
      sf[cn] = mfma_bf16(qf0, b0, sf[cn]);
      sf[cn] = mfma_bf16(qf1, b1, sf[cn]);
    }
    float tmax[4];
#pragma unroll
    for (int j = 0; j < 4; ++j)
      tmax[j] = fmaxf(fmaxf(sf[0][j], sf[1][j]), fmaxf(sf[2][j], sf[3][j]));
#pragma unroll
    for (int off = 1; off < 16; off <<= 1)
#pragma unroll
      for (int j = 0; j < 4; ++j)
        tmax[j] = fmaxf(tmax[j], __shfl_xor(tmax[j], off));
    float corr[4], psum[4];
#pragma unroll
    for (int j = 0; j < 4; ++j) {
      float mn = fmaxf(m[j], tmax[j]);
      corr[j] = EXP2((m[j] - mn) * LOG2E);
      m[j] = mn;
      psum[j] = 0.f;
    }
#pragma unroll
    for (int cn = 0; cn < 4; ++cn)
#pragma unroll
      for (int j = 0; j < 4; ++j) {
        float pv = EXP2((sf[cn][j] - m[j]) * LOG2E);
        psum[j] += pv;
        P[(lg * 4 + j) * 72 + cn * 16 + li] = f2bf(pv);
      }
#pragma unroll
    for (int off = 1; off < 16; off <<= 1)
#pragma unroll
      for (int j = 0; j < 4; ++j)
        psum[j] += __shfl_xor(psum[j], off);
#pragma unroll
    for (int j = 0; j < 4; ++j) lsum[j] = lsum[j] * corr[j] + psum[j];
#pragma unroll
    for (int nf = 0; nf < 4; ++nf) {
      acc[nf][0] *= corr[0]; acc[nf][1] *= corr[1];
      acc[nf][2] *= corr[2]; acc[nf][3] *= corr[3];
    }
#pragma unroll
    for (int pk = 0; pk < 2; ++pk) {
      frag8 pa = *(const frag8*)(&P[li * 72 + pk * 32 + lg * 8]);
#pragma unroll
      for (int nf = 0; nf < 4; ++nf) {
        const unsigned short* vp =
            Vh + (size_t)(nf * 16 + li) * 4096 + kbase + pk * 32 + lg * 8;
        frag8 vb = *(const frag8*)vp;
        acc[nf] = mfma_bf16(pa, vb, acc[nf]);
      }
    }
  }
#pragma unroll
  for (int nf = 0; nf < 4; ++nf)
#pragma unroll
    for (int j = 0; j < 4; ++j) {
      int row = s0 + w * 16 + lg * 4 + j;
      int e = nf * 16 + li;
      ctx[(size_t)row * 768 + h * 64 + e] = f2bf(acc[nf][j] / lsum[j]);
    }
}

// ---------------------------------------------------------------------------
// Output projection: out[s,j] = sum_i ctx[s,i]*woT[j,i] + bo[j]  -> F32 d_out
__global__ __launch_bounds__(256) void k_proj(
    const unsigned short* __restrict__ ctx, const unsigned short* __restrict__ woT,
    const float* __restrict__ bo, float* __restrict__ out) {
  __shared__ __align__(16) unsigned short As[64 * 72];
  __shared__ __align__(16) unsigned short Bs[64 * 72];
  const int s0 = blockIdx.x * 64, j0 = blockIdx.y * 64;
  const int tid = threadIdx.x;
  const int w = tid >> 6, l = tid & 63;
  const int lg = l >> 4, li = l & 15;
  const int wm = w >> 1, wn = w & 1;
  facc4 acc[2][2];
#pragma unroll
  for (int i = 0; i < 2; ++i)
#pragma unroll
    for (int j = 0; j < 2; ++j) acc[i][j] = (facc4){0.f, 0.f, 0.f, 0.f};

  const int rA = tid >> 3;
  const int c8 = (tid & 7) * 8;

  for (int k0 = 0; k0 < 768; k0 += 64) {
    frag8 av[2], bw[2];
#pragma unroll
    for (int i = 0; i < 2; ++i) {
      av[i] = *(const frag8*)(ctx + (size_t)(s0 + i * 32 + rA) * 768 + k0 + c8);
      bw[i] = *(const frag8*)(woT + (size_t)(j0 + i * 32 + rA) * 768 + k0 + c8);
    }
#pragma unroll
    for (int i = 0; i < 2; ++i) {
      *(frag8*)(&As[(i * 32 + rA) * 72 + c8]) = av[i];
      *(frag8*)(&Bs[(i * 32 + rA) * 72 + c8]) = bw[i];
    }
    __syncthreads();
#pragma unroll
    for (int kk = 0; kk < 2; ++kk) {
      const int ce = kk * 32 + lg * 8;
      frag8 a[2], b[2];
#pragma unroll
      for (int mf = 0; mf < 2; ++mf)
        a[mf] = *(const frag8*)(&As[(wm * 32 + mf * 16 + li) * 72 + ce]);
#pragma unroll
      for (int nf = 0; nf < 2; ++nf)
        b[nf] = *(const frag8*)(&Bs[(wn * 32 + nf * 16 + li) * 72 + ce]);
#pragma unroll
      for (int mf = 0; mf < 2; ++mf)
#pragma unroll
        for (int nf = 0; nf < 2; ++nf)
          acc[mf][nf] = mfma_bf16(a[mf], b[nf], acc[mf][nf]);
    }
    __syncthreads();
  }
#pragma unroll
  for (int nf = 0; nf < 2; ++nf) {
    int jc = j0 + wn * 32 + nf * 16 + li;
    float bb = bo[jc];
#pragma unroll
    for (int mf = 0; mf < 2; ++mf)
#pragma unroll
      for (int j = 0; j < 4; ++j) {
        int s = s0 + wm * 32 + mf * 16 + lg * 4 + j;
        out[(size_t)s * 768 + jc] = acc[mf][nf][j] + bb;   // F32 STORE
      }
  }
}

// ---------------------------------------------------------------------------
extern "C" void kernel_launch(void* const* d_in, const int* in_sizes, int n_in,
                              void* d_out, int out_size, void* d_ws, size_t ws_size,
                              hipStream_t stream) {
  const float* x  = (const float*)d_in[0];
  const float* wq = (const float*)d_in[1];
  const float* bq = (const float*)d_in[2];
  const float* wk = (const float*)d_in[3];
  const float* bk = (const float*)d_in[4];
  const float* wv = (const float*)d_in[5];
  const float* bv = (const float*)d_in[6];
  const float* wo = (const float*)d_in[7];
  const float* bo = (const float*)d_in[8];
  float* out = (float*)d_out;   // F32 output buffer (proven round 3/4)

  char* ws = (char*)d_ws;
  unsigned short* xb  = (unsigned short*)(ws);
  unsigned short* wT  = (unsigned short*)(ws + 6291456);
  unsigned short* woT = (unsigned short*)(ws + 9830400);
  unsigned short* qd  = (unsigned short*)(ws + 11010048);
  unsigned short* kd  = (unsigned short*)(ws + 17301504);
  unsigned short* vTd = (unsigned short*)(ws + 23592960);
  unsigned short* ctx = (unsigned short*)(ws + 29884416);

  k_cvt_x<<<1536, 256, 0, stream>>>(x, xb);
  k_prep_w<<<576, 256, 0, stream>>>(wq, wk, wv, wo,
                                    wT, wT + 589824, wT + 1179648, woT);
  k_qkv<<<dim3(32, 36), 256, 0, stream>>>(xb, wT, bq, bk, bv, qd, kd, vTd);
  k_attn<<<768, 256, 0, stream>>>(qd, kd, vTd, ctx);
  k_proj<<<dim3(64, 12), 256, 0, stream>>>(ctx, woT, bo, out);
}